// Round 15
// baseline (453.457 us; speedup 1.0000x reference)
//
#include <hip/hip_runtime.h>

#define B_ 256
#define T_ 1024
#define E_ 32
#define H_ 128
#define NOBS_ 1048576
#define L2E 1.4426950408889634f
#define CLM 30.0f

#define HROW 144              // bytes per h row in LDS (128 i8 + 16 pad)
#define HBUF (4 * HROW)       // one h buffer (4 rows)

typedef __attribute__((ext_vector_type(8))) short bf16x8;
typedef __attribute__((ext_vector_type(4))) float f32x4;
typedef __attribute__((ext_vector_type(4))) int   i32x4;

// LDS-only barrier: drains LDS ops only; global loads/stores stay in flight.
#define LDS_BARRIER() asm volatile("s_waitcnt lgkmcnt(0)\n\ts_barrier" ::: "memory")

__device__ __forceinline__ short f2bf(float x) {
    unsigned u = __float_as_uint(x);
    unsigned r = u + 0x7FFFu + ((u >> 16) & 1u);   // RNE
    return (short)(r >> 16);
}

__device__ __forceinline__ bf16x8 pack8(float4 lo, float4 hi) {
    int x0, x1, x2, x3;
    asm("v_cvt_pk_bf16_f32 %0, %1, %2" : "=v"(x0) : "v"(lo.x), "v"(lo.y));
    asm("v_cvt_pk_bf16_f32 %0, %1, %2" : "=v"(x1) : "v"(lo.z), "v"(lo.w));
    asm("v_cvt_pk_bf16_f32 %0, %1, %2" : "=v"(x2) : "v"(hi.x), "v"(hi.y));
    asm("v_cvt_pk_bf16_f32 %0, %1, %2" : "=v"(x3) : "v"(hi.z), "v"(hi.w));
    i32x4 xi; xi[0] = x0; xi[1] = x1; xi[2] = x2; xi[3] = x3;
    return __builtin_bit_cast(bf16x8, xi);
}

// ---------------- embedding kernel (proven; writes f32 + bf16 copy) ----------------
__global__ void embed_kernel(const int* __restrict__ obs_ids,
                             const int* __restrict__ obs_slot,
                             const int* __restrict__ action_ids,
                             const int* __restrict__ is_action,
                             const float* __restrict__ action_emb,
                             const float* __restrict__ obs_emb,
                             float* __restrict__ embedded,
                             unsigned short* __restrict__ xbf) {
    __shared__ float s_act[5 * E_];
    __shared__ float s_obs[11 * E_];
    for (int i = threadIdx.x; i < 5 * E_; i += blockDim.x) s_act[i] = action_emb[i];
    for (int i = threadIdx.x; i < 11 * E_; i += blockDim.x) s_obs[i] = obs_emb[i];
    __syncthreads();

    int s = blockIdx.x * blockDim.x + threadIdx.x;
    if (s >= B_ * T_) return;

    float acc[E_];
    if (is_action[s]) {
        int a = action_ids[s];
        #pragma unroll
        for (int e = 0; e < E_; e++) acc[e] = s_act[a * E_ + e];
    } else {
        #pragma unroll
        for (int e = 0; e < E_; e++) acc[e] = 0.0f;
        int lo = 0, hi = NOBS_;
        while (lo < hi) {
            int mid = (lo + hi) >> 1;
            if (obs_slot[mid] < s) lo = mid + 1; else hi = mid;
        }
        int j = lo;
        while (j < NOBS_ && obs_slot[j] == s) {
            int id = obs_ids[j];
            #pragma unroll
            for (int e = 0; e < E_; e++) acc[e] += s_obs[id * E_ + e];
            j++;
        }
    }
    float4* dst = (float4*)(embedded + (size_t)s * E_);
    #pragma unroll
    for (int q = 0; q < E_ / 4; q++) {
        float4 v; v.x = acc[4*q]; v.y = acc[4*q+1]; v.z = acc[4*q+2]; v.w = acc[4*q+3];
        dst[q] = v;
    }
    if (xbf) {
        unsigned short tmp[E_];
        #pragma unroll
        for (int e = 0; e < E_; e++) tmp[e] = (unsigned short)f2bf(acc[e]);
        int4* d2 = (int4*)(xbf + (size_t)s * E_);
        #pragma unroll
        for (int q = 0; q < E_ / 8; q++) d2[q] = ((const int4*)tmp)[q];
    }
}

// ---------------- LSTM kernel: 4-t-batched x-GEMM + split-acc i8 h-part ----------------
// R14 structure (440 us) with ONE chain cut: the two K-tile i8 MFMAs use
// INDEPENDENT accumulators (issued back-to-back, no acc dependency) and are
// combined by a single integer add of element 0 (the only element consumed).
// Removes one MFMA latency from the t-recurrence critical path; exact math.
template<bool BF16X>
__launch_bounds__(512, 2)
__global__ void lstm_kernel(const float* __restrict__ embedded,
                            const unsigned short* __restrict__ xbf,
                            const int* __restrict__ lengths,
                            const float* __restrict__ W_ih,
                            const float* __restrict__ W_hh,
                            const float* __restrict__ b_ih,
                            const float* __restrict__ b_hh,
                            float* __restrict__ outputs,
                            float* __restrict__ h_out,
                            float* __restrict__ c_out) {
    __shared__ __align__(16) char h_lds[2 * HBUF];   // double-buffered [4][HROW] i8

    const int tid  = threadIdx.x;
    const int lane = tid & 63;
    const int wave = tid >> 6;
    const int row0 = blockIdx.x * 4;

    const int col16  = (wave << 4) + (lane & 15);
    const int kgrp8  = (lane >> 4) * 8;
    const int kgrp16 = (lane >> 4) * 16;
    const int brow   = (lane & 15) >> 2;    // batch row for A frags (x and h)
    const int toff   = (lane & 15) & 3;     // t-offset within 4-step group (x A rows)
    const int g_own  = lane >> 4;           // batch row this lane OWNS

    // ---- weights: x-part bf16 (log2e-scaled; 2x for g), h-part i8 ----
    bf16x8 wx[4]; f32x4 biasv[4]; i32x4 wh[4][2]; float dq[4];
    #pragma unroll
    for (int gt = 0; gt < 4; gt++) {
        const float scale = (gt == 2) ? (2.0f * L2E) : L2E;
        const int gcol = gt * H_ + col16;
        {
            const float* p = W_ih + (size_t)gcol * E_ + kgrp8;
            bf16x8 v;
            #pragma unroll
            for (int j = 0; j < 8; j++) v[j] = f2bf(p[j] * scale);
            wx[gt] = v;
        }
        biasv[gt] = (f32x4)((b_ih[gcol] + b_hh[gcol]) * scale);

        const float* q = W_hh + (size_t)gcol * H_;
        float m = 0.0f;
        #pragma unroll
        for (int t2 = 0; t2 < 2; t2++)
            #pragma unroll
            for (int j = 0; j < 16; j++)
                m = fmaxf(m, fabsf(q[t2 * 64 + kgrp16 + j]));
        m = fmaxf(m, __shfl_xor(m, 16));
        m = fmaxf(m, __shfl_xor(m, 32));
        const float s = 127.0f / m;
        dq[gt] = scale * m * (1.0f / (127.0f * 127.0f));
        #pragma unroll
        for (int t2 = 0; t2 < 2; t2++) {
            i32x4 v;
            #pragma unroll
            for (int d = 0; d < 4; d++) {
                int word = 0;
                #pragma unroll
                for (int b2 = 0; b2 < 4; b2++) {
                    int qi = (int)rintf(q[t2 * 64 + kgrp16 + d * 4 + b2] * s);
                    word |= (qi & 0xFF) << (b2 * 8);
                }
                v[d] = word;
            }
            wh[gt][t2] = v;
        }
    }

    const int len = lengths[row0 + g_own];
    float cr = 0.0f, hr = 0.0f;

    // x A-frag source: row (row0+brow), t = tg + toff, k = kgrp8..kgrp8+7
    const unsigned short* xpb = xbf + ((size_t)(row0 + brow) * T_ + toff) * E_ + kgrp8;
    const float*          xpf = embedded + ((size_t)(row0 + brow) * T_ + toff) * E_ + kgrp8;

    const int rbase = brow * HROW + kgrp16;
    const int wofs  = g_own * HROW + col16;
    float* const out_base = outputs + (size_t)(row0 + g_own) * T_ * H_ + col16;

    for (int i = tid; i < 2 * HBUF; i += 512) h_lds[i] = 0;
    __syncthreads();

    int4 xf0, xf1;
    float4 fl0, fh0, fl1, fh1;
    auto loadx = [&](int tg, int4& xi4, float4& fl, float4& fh) {
        if (BF16X) {
            xi4 = *(const int4*)(xpb + (size_t)tg * E_);
        } else {
            fl = *(const float4*)(xpf + (size_t)tg * E_);
            fh = *(const float4*)(xpf + (size_t)tg * E_ + 4);
        }
    };
    auto mkfrag = [&](const int4& xi4, const float4& fl, const float4& fh) -> bf16x8 {
        if (BF16X) return __builtin_bit_cast(bf16x8, xi4);
        return pack8(fl, fh);
    };

    loadx(0, xf0, fl0, fh0);
    loadx(4, xf1, fl1, fh1);

    // one 4-step group: x-burst (4 bf16 MFMAs; regs 0..3 = t = tg..tg+3),
    // prefetch next-next group's x, then 4 h-steps with split-acc i8 MFMA.
    auto group = [&](int tg, const int4& xf_u, const float4& fl_u, const float4& fh_u,
                     int4& xf_p, float4& fl_p, float4& fh_p, bool PF) {
        bf16x8 xa = mkfrag(xf_u, fl_u, fh_u);
        f32x4 accf[4];
        __builtin_amdgcn_s_setprio(1);
        #pragma unroll
        for (int gt = 0; gt < 4; gt++)
            accf[gt] = __builtin_amdgcn_mfma_f32_16x16x32_bf16(xa, wx[gt], biasv[gt], 0, 0, 0);
        __builtin_amdgcn_s_setprio(0);
        if (PF) loadx(tg + 8, xf_p, fl_p, fh_p);   // in flight across the group

        #pragma unroll
        for (int i = 0; i < 4; i++) {
            const int t  = tg + i;
            const int RD = (i & 1) ? HBUF : 0;
            const int WR = RD ^ HBUF;

            i32x4 ah0 = *(const i32x4*)&h_lds[RD + rbase];
            i32x4 ah1 = *(const i32x4*)&h_lds[RD + rbase + 64];

            // independent accumulators: both MFMAs issue back-to-back with no
            // acc dependency -> one MFMA latency on the chain instead of two
            __builtin_amdgcn_s_setprio(1);
            i32x4 accp[4], accq[4];
            #pragma unroll
            for (int gt = 0; gt < 4; gt++) {
                accp[gt] = __builtin_amdgcn_mfma_i32_16x16x64_i8(ah0, wh[gt][0], (i32x4)0, 0, 0, 0);
                accq[gt] = __builtin_amdgcn_mfma_i32_16x16x64_i8(ah1, wh[gt][1], (i32x4)0, 0, 0, 0);
            }
            __builtin_amdgcn_s_setprio(0);

            // EW (shared-rcp, verified); only element 0 of each acc is used
            float a_i = fmaf((float)(accp[0][0] + accq[0][0]), dq[0], accf[0][i]);
            float a_f = fmaf((float)(accp[1][0] + accq[1][0]), dq[1], accf[1][i]);
            float a_g = fmaf((float)(accp[2][0] + accq[2][0]), dq[2], accf[2][i]);
            float a_o = fmaf((float)(accp[3][0] + accq[3][0]), dq[3], accf[3][i]);
            float Ai = exp2f(fminf(-a_i, CLM));
            float Af = exp2f(fminf(-a_f, CLM));
            float Eg = exp2f(fminf(a_g, CLM));
            float pAi = 1.0f + Ai, pAf = 1.0f + Af, pEg = Eg + 1.0f;
            float D  = pAi * pEg;
            float R  = __builtin_amdgcn_rcpf(D * pAf);
            float f_ = D * R;                         // sigmoid(a_f)
            float ig = (Eg - 1.0f) * pAf * R;         // sigmoid(a_i)*tanh(g)
            float c_new = fmaf(f_, cr, ig);
            float Ec = exp2f(fminf(c_new * (2.0f * L2E), CLM));
            float Ao = exp2f(fminf(-a_o, CLM));
            float Rh = __builtin_amdgcn_rcpf((1.0f + Ao) * (Ec + 1.0f));
            float h_new = (Ec - 1.0f) * Rh;           // sigmoid(a_o)*tanh(c)
            bool m = (t < len);
            cr = m ? c_new : cr;
            hr = m ? h_new : hr;

            unsigned qb = __float_as_uint(fmaf(hr, 127.0f, 12582912.0f));  // RNE i8
            h_lds[WR + wofs] = (char)qb;
            out_base[(size_t)t * H_] = m ? h_new : 0.0f;   // fire-and-forget

            LDS_BARRIER();
        }
    };

    for (int tg = 0; tg < T_; tg += 8) {
        group(tg,     xf0, fl0, fh0, xf0, fl0, fh0, tg + 8 < T_);
        group(tg + 4, xf1, fl1, fh1, xf1, fl1, fh1, tg + 12 < T_);
    }

    h_out[(size_t)(row0 + g_own) * H_ + col16] = hr;
    c_out[(size_t)(row0 + g_own) * H_ + col16] = cr;
}

extern "C" void kernel_launch(void* const* d_in, const int* in_sizes, int n_in,
                              void* d_out, int out_size, void* d_ws, size_t ws_size,
                              hipStream_t stream) {
    const int*   obs_ids       = (const int*)d_in[0];
    const int*   obs_slot      = (const int*)d_in[1];
    const int*   action_ids    = (const int*)d_in[2];
    const int*   is_action     = (const int*)d_in[3];
    const int*   input_lengths = (const int*)d_in[4];
    const float* action_emb    = (const float*)d_in[5];
    const float* obs_emb       = (const float*)d_in[6];
    const float* W_ih          = (const float*)d_in[7];
    const float* W_hh          = (const float*)d_in[8];
    const float* b_ih          = (const float*)d_in[9];
    const float* b_hh          = (const float*)d_in[10];

    float* out      = (float*)d_out;
    float* outputs  = out;                                   // [B,T,H]
    float* h_out    = out + (size_t)B_ * T_ * H_;            // [1,B,H]
    float* c_out    = h_out + (size_t)B_ * H_;               // [1,B,H]
    float* embedded = c_out + (size_t)B_ * H_;               // [B,T,E]

    const size_t xbf_bytes = (size_t)B_ * T_ * E_ * sizeof(unsigned short);
    const bool use_bf16x = (ws_size >= xbf_bytes);
    unsigned short* xbf = use_bf16x ? (unsigned short*)d_ws : nullptr;

    hipLaunchKernelGGL(embed_kernel, dim3((B_ * T_ + 255) / 256), dim3(256), 0, stream,
                       obs_ids, obs_slot, action_ids, is_action, action_emb, obs_emb,
                       embedded, xbf);

    if (use_bf16x) {
        hipLaunchKernelGGL((lstm_kernel<true>), dim3(B_ / 4), dim3(512), 0, stream,
                           embedded, xbf, input_lengths, W_ih, W_hh, b_ih, b_hh,
                           outputs, h_out, c_out);
    } else {
        hipLaunchKernelGGL((lstm_kernel<false>), dim3(B_ / 4), dim3(512), 0, stream,
                           embedded, xbf, input_lengths, W_ih, W_hh, b_ih, b_hh,
                           outputs, h_out, c_out);
    }
}

// Round 16
// 440.020 us; speedup vs baseline: 1.0305x; 1.0305x over previous
//
#include <hip/hip_runtime.h>

#define B_ 256
#define T_ 1024
#define E_ 32
#define H_ 128
#define NOBS_ 1048576
#define L2E 1.4426950408889634f
#define CLM 30.0f

#define HROW 144              // bytes per h row in LDS (128 i8 + 16 pad)
#define HBUF (4 * HROW)       // one h buffer (4 rows)

typedef __attribute__((ext_vector_type(8))) short bf16x8;
typedef __attribute__((ext_vector_type(4))) float f32x4;
typedef __attribute__((ext_vector_type(4))) int   i32x4;

// LDS-only barrier: drains LDS ops only; global loads/stores stay in flight.
#define LDS_BARRIER() asm volatile("s_waitcnt lgkmcnt(0)\n\ts_barrier" ::: "memory")

__device__ __forceinline__ short f2bf(float x) {
    unsigned u = __float_as_uint(x);
    unsigned r = u + 0x7FFFu + ((u >> 16) & 1u);   // RNE
    return (short)(r >> 16);
}

__device__ __forceinline__ bf16x8 pack8(float4 lo, float4 hi) {
    int x0, x1, x2, x3;
    asm("v_cvt_pk_bf16_f32 %0, %1, %2" : "=v"(x0) : "v"(lo.x), "v"(lo.y));
    asm("v_cvt_pk_bf16_f32 %0, %1, %2" : "=v"(x1) : "v"(lo.z), "v"(lo.w));
    asm("v_cvt_pk_bf16_f32 %0, %1, %2" : "=v"(x2) : "v"(hi.x), "v"(hi.y));
    asm("v_cvt_pk_bf16_f32 %0, %1, %2" : "=v"(x3) : "v"(hi.z), "v"(hi.w));
    i32x4 xi; xi[0] = x0; xi[1] = x1; xi[2] = x2; xi[3] = x3;
    return __builtin_bit_cast(bf16x8, xi);
}

// ---------------- embedding kernel (proven; writes f32 + bf16 copy) ----------------
__global__ void embed_kernel(const int* __restrict__ obs_ids,
                             const int* __restrict__ obs_slot,
                             const int* __restrict__ action_ids,
                             const int* __restrict__ is_action,
                             const float* __restrict__ action_emb,
                             const float* __restrict__ obs_emb,
                             float* __restrict__ embedded,
                             unsigned short* __restrict__ xbf) {
    __shared__ float s_act[5 * E_];
    __shared__ float s_obs[11 * E_];
    for (int i = threadIdx.x; i < 5 * E_; i += blockDim.x) s_act[i] = action_emb[i];
    for (int i = threadIdx.x; i < 11 * E_; i += blockDim.x) s_obs[i] = obs_emb[i];
    __syncthreads();

    int s = blockIdx.x * blockDim.x + threadIdx.x;
    if (s >= B_ * T_) return;

    float acc[E_];
    if (is_action[s]) {
        int a = action_ids[s];
        #pragma unroll
        for (int e = 0; e < E_; e++) acc[e] = s_act[a * E_ + e];
    } else {
        #pragma unroll
        for (int e = 0; e < E_; e++) acc[e] = 0.0f;
        int lo = 0, hi = NOBS_;
        while (lo < hi) {
            int mid = (lo + hi) >> 1;
            if (obs_slot[mid] < s) lo = mid + 1; else hi = mid;
        }
        int j = lo;
        while (j < NOBS_ && obs_slot[j] == s) {
            int id = obs_ids[j];
            #pragma unroll
            for (int e = 0; e < E_; e++) acc[e] += s_obs[id * E_ + e];
            j++;
        }
    }
    float4* dst = (float4*)(embedded + (size_t)s * E_);
    #pragma unroll
    for (int q = 0; q < E_ / 4; q++) {
        float4 v; v.x = acc[4*q]; v.y = acc[4*q+1]; v.z = acc[4*q+2]; v.w = acc[4*q+3];
        dst[q] = v;
    }
    if (xbf) {
        unsigned short tmp[E_];
        #pragma unroll
        for (int e = 0; e < E_; e++) tmp[e] = (unsigned short)f2bf(acc[e]);
        int4* d2 = (int4*)(xbf + (size_t)s * E_);
        #pragma unroll
        for (int q = 0; q < E_ / 8; q++) d2[q] = ((const int4*)tmp)[q];
    }
}

// ---------------- LSTM kernel: 4-timestep-batched x-GEMM + i8 h-part ----------------
// (R14, best measured: 440 us.) 8 waves x RPB=4, one gate element per lane.
// x-part packs 4 timesteps into the MFMA M-dimension (A row r = (batch row
// r>>2, t + (r&3)), 16 distinct rows, no dup) so ONE bf16 MFMA per gate covers
// 4 steps: C row 4g+i = gates_x(batch g, t+i) -> lane g's accf[gt][i] is its
// own gate for step t+i. h-part: i8 16x16x64, accumulator-chained (split-acc
// variant measured -3%, reverted).
template<bool BF16X>
__launch_bounds__(512, 2)
__global__ void lstm_kernel(const float* __restrict__ embedded,
                            const unsigned short* __restrict__ xbf,
                            const int* __restrict__ lengths,
                            const float* __restrict__ W_ih,
                            const float* __restrict__ W_hh,
                            const float* __restrict__ b_ih,
                            const float* __restrict__ b_hh,
                            float* __restrict__ outputs,
                            float* __restrict__ h_out,
                            float* __restrict__ c_out) {
    __shared__ __align__(16) char h_lds[2 * HBUF];   // double-buffered [4][HROW] i8

    const int tid  = threadIdx.x;
    const int lane = tid & 63;
    const int wave = tid >> 6;
    const int row0 = blockIdx.x * 4;

    const int col16  = (wave << 4) + (lane & 15);
    const int kgrp8  = (lane >> 4) * 8;
    const int kgrp16 = (lane >> 4) * 16;
    const int brow   = (lane & 15) >> 2;    // batch row for A frags (x and h)
    const int toff   = (lane & 15) & 3;     // t-offset within 4-step group (x A rows)
    const int g_own  = lane >> 4;           // batch row this lane OWNS

    // ---- weights: x-part bf16 (log2e-scaled; 2x for g), h-part i8 ----
    bf16x8 wx[4]; f32x4 biasv[4]; i32x4 wh[4][2]; float dq[4];
    #pragma unroll
    for (int gt = 0; gt < 4; gt++) {
        const float scale = (gt == 2) ? (2.0f * L2E) : L2E;
        const int gcol = gt * H_ + col16;
        {
            const float* p = W_ih + (size_t)gcol * E_ + kgrp8;
            bf16x8 v;
            #pragma unroll
            for (int j = 0; j < 8; j++) v[j] = f2bf(p[j] * scale);
            wx[gt] = v;
        }
        biasv[gt] = (f32x4)((b_ih[gcol] + b_hh[gcol]) * scale);

        const float* q = W_hh + (size_t)gcol * H_;
        float m = 0.0f;
        #pragma unroll
        for (int t2 = 0; t2 < 2; t2++)
            #pragma unroll
            for (int j = 0; j < 16; j++)
                m = fmaxf(m, fabsf(q[t2 * 64 + kgrp16 + j]));
        m = fmaxf(m, __shfl_xor(m, 16));
        m = fmaxf(m, __shfl_xor(m, 32));
        const float s = 127.0f / m;
        dq[gt] = scale * m * (1.0f / (127.0f * 127.0f));
        #pragma unroll
        for (int t2 = 0; t2 < 2; t2++) {
            i32x4 v;
            #pragma unroll
            for (int d = 0; d < 4; d++) {
                int word = 0;
                #pragma unroll
                for (int b2 = 0; b2 < 4; b2++) {
                    int qi = (int)rintf(q[t2 * 64 + kgrp16 + d * 4 + b2] * s);
                    word |= (qi & 0xFF) << (b2 * 8);
                }
                v[d] = word;
            }
            wh[gt][t2] = v;
        }
    }

    const int len = lengths[row0 + g_own];
    float cr = 0.0f, hr = 0.0f;

    // x A-frag source: row (row0+brow), t = tg + toff, k = kgrp8..kgrp8+7
    const unsigned short* xpb = xbf + ((size_t)(row0 + brow) * T_ + toff) * E_ + kgrp8;
    const float*          xpf = embedded + ((size_t)(row0 + brow) * T_ + toff) * E_ + kgrp8;

    const int rbase = brow * HROW + kgrp16;
    const int wofs  = g_own * HROW + col16;
    float* const out_base = outputs + (size_t)(row0 + g_own) * T_ * H_ + col16;

    for (int i = tid; i < 2 * HBUF; i += 512) h_lds[i] = 0;
    __syncthreads();

    int4 xf0, xf1;
    float4 fl0, fh0, fl1, fh1;
    auto loadx = [&](int tg, int4& xi4, float4& fl, float4& fh) {
        if (BF16X) {
            xi4 = *(const int4*)(xpb + (size_t)tg * E_);
        } else {
            fl = *(const float4*)(xpf + (size_t)tg * E_);
            fh = *(const float4*)(xpf + (size_t)tg * E_ + 4);
        }
    };
    auto mkfrag = [&](const int4& xi4, const float4& fl, const float4& fh) -> bf16x8 {
        if (BF16X) return __builtin_bit_cast(bf16x8, xi4);
        return pack8(fl, fh);
    };

    loadx(0, xf0, fl0, fh0);
    loadx(4, xf1, fl1, fh1);

    // one 4-step group: x-burst (4 bf16 MFMAs; regs 0..3 = t = tg..tg+3),
    // prefetch next-next group's x, then 4 h-steps.
    auto group = [&](int tg, const int4& xf_u, const float4& fl_u, const float4& fh_u,
                     int4& xf_p, float4& fl_p, float4& fh_p, bool PF) {
        bf16x8 xa = mkfrag(xf_u, fl_u, fh_u);
        f32x4 accf[4];
        __builtin_amdgcn_s_setprio(1);
        #pragma unroll
        for (int gt = 0; gt < 4; gt++)
            accf[gt] = __builtin_amdgcn_mfma_f32_16x16x32_bf16(xa, wx[gt], biasv[gt], 0, 0, 0);
        __builtin_amdgcn_s_setprio(0);
        if (PF) loadx(tg + 8, xf_p, fl_p, fh_p);   // in flight across the group

        #pragma unroll
        for (int i = 0; i < 4; i++) {
            const int t  = tg + i;
            const int RD = (i & 1) ? HBUF : 0;
            const int WR = RD ^ HBUF;

            i32x4 ah0 = *(const i32x4*)&h_lds[RD + rbase];
            i32x4 ah1 = *(const i32x4*)&h_lds[RD + rbase + 64];

            __builtin_amdgcn_s_setprio(1);
            i32x4 acci[4];
            #pragma unroll
            for (int gt = 0; gt < 4; gt++)
                acci[gt] = __builtin_amdgcn_mfma_i32_16x16x64_i8(ah0, wh[gt][0], (i32x4)0, 0, 0, 0);
            #pragma unroll
            for (int gt = 0; gt < 4; gt++)
                acci[gt] = __builtin_amdgcn_mfma_i32_16x16x64_i8(ah1, wh[gt][1], acci[gt], 0, 0, 0);
            __builtin_amdgcn_s_setprio(0);

            // EW (shared-rcp, verified); compile-time reg index i (rule #20)
            float a_i = fmaf((float)acci[0][0], dq[0], accf[0][i]);
            float a_f = fmaf((float)acci[1][0], dq[1], accf[1][i]);
            float a_g = fmaf((float)acci[2][0], dq[2], accf[2][i]);
            float a_o = fmaf((float)acci[3][0], dq[3], accf[3][i]);
            float Ai = exp2f(fminf(-a_i, CLM));
            float Af = exp2f(fminf(-a_f, CLM));
            float Eg = exp2f(fminf(a_g, CLM));
            float pAi = 1.0f + Ai, pAf = 1.0f + Af, pEg = Eg + 1.0f;
            float D  = pAi * pEg;
            float R  = __builtin_amdgcn_rcpf(D * pAf);
            float f_ = D * R;                         // sigmoid(a_f)
            float ig = (Eg - 1.0f) * pAf * R;         // sigmoid(a_i)*tanh(g)
            float c_new = fmaf(f_, cr, ig);
            float Ec = exp2f(fminf(c_new * (2.0f * L2E), CLM));
            float Ao = exp2f(fminf(-a_o, CLM));
            float Rh = __builtin_amdgcn_rcpf((1.0f + Ao) * (Ec + 1.0f));
            float h_new = (Ec - 1.0f) * Rh;           // sigmoid(a_o)*tanh(c)
            bool m = (t < len);
            cr = m ? c_new : cr;
            hr = m ? h_new : hr;

            unsigned qb = __float_as_uint(fmaf(hr, 127.0f, 12582912.0f));  // RNE i8
            h_lds[WR + wofs] = (char)qb;
            out_base[(size_t)t * H_] = m ? h_new : 0.0f;   // fire-and-forget

            LDS_BARRIER();
        }
    };

    for (int tg = 0; tg < T_; tg += 8) {
        group(tg,     xf0, fl0, fh0, xf0, fl0, fh0, tg + 8 < T_);
        group(tg + 4, xf1, fl1, fh1, xf1, fl1, fh1, tg + 12 < T_);
    }

    h_out[(size_t)(row0 + g_own) * H_ + col16] = hr;
    c_out[(size_t)(row0 + g_own) * H_ + col16] = cr;
}

extern "C" void kernel_launch(void* const* d_in, const int* in_sizes, int n_in,
                              void* d_out, int out_size, void* d_ws, size_t ws_size,
                              hipStream_t stream) {
    const int*   obs_ids       = (const int*)d_in[0];
    const int*   obs_slot      = (const int*)d_in[1];
    const int*   action_ids    = (const int*)d_in[2];
    const int*   is_action     = (const int*)d_in[3];
    const int*   input_lengths = (const int*)d_in[4];
    const float* action_emb    = (const float*)d_in[5];
    const float* obs_emb       = (const float*)d_in[6];
    const float* W_ih          = (const float*)d_in[7];
    const float* W_hh          = (const float*)d_in[8];
    const float* b_ih          = (const float*)d_in[9];
    const float* b_hh          = (const float*)d_in[10];

    float* out      = (float*)d_out;
    float* outputs  = out;                                   // [B,T,H]
    float* h_out    = out + (size_t)B_ * T_ * H_;            // [1,B,H]
    float* c_out    = h_out + (size_t)B_ * H_;               // [1,B,H]
    float* embedded = c_out + (size_t)B_ * H_;               // [B,T,E]

    const size_t xbf_bytes = (size_t)B_ * T_ * E_ * sizeof(unsigned short);
    const bool use_bf16x = (ws_size >= xbf_bytes);
    unsigned short* xbf = use_bf16x ? (unsigned short*)d_ws : nullptr;

    hipLaunchKernelGGL(embed_kernel, dim3((B_ * T_ + 255) / 256), dim3(256), 0, stream,
                       obs_ids, obs_slot, action_ids, is_action, action_emb, obs_emb,
                       embedded, xbf);

    if (use_bf16x) {
        hipLaunchKernelGGL((lstm_kernel<true>), dim3(B_ / 4), dim3(512), 0, stream,
                           embedded, xbf, input_lengths, W_ih, W_hh, b_ih, b_hh,
                           outputs, h_out, c_out);
    } else {
        hipLaunchKernelGGL((lstm_kernel<false>), dim3(B_ / 4), dim3(512), 0, stream,
                           embedded, xbf, input_lengths, W_ih, W_hh, b_ih, b_hh,
                           outputs, h_out, c_out);
    }
}